// Round 3
// baseline (40.670 us; speedup 1.0000x reference)
//
#include <hip/hip_runtime.h>
#include <hip/hip_bf16.h>

#define NCLS 64
#define NSUP 5
#define NQRY 15
#define DIM  4096
#define NQTOT (NCLS * NQRY)   // 960
#define NQT   (NQTOT / 16)    // 60 query tiles
#define KC    4               // K-chunks per q-tile

typedef __attribute__((ext_vector_type(8))) short short8;
typedef __attribute__((ext_vector_type(4))) float f32x4;

__device__ __forceinline__ unsigned short f2bf(float f) {
    unsigned int u = __float_as_uint(f);
    u += 0x7FFFu + ((u >> 16) & 1u);   // RNE
    return (unsigned short)(u >> 16);
}
__device__ __forceinline__ float bf2f(unsigned short s) {
    return __uint_as_float(((unsigned int)s) << 16);
}

// K1: prototypes. 256 blocks: class c = b>>2, d-chunk dc = b&3 (1024 dims).
// Writes bf16 P[c][D], partial ||p||^2 -> pnp[c*4+dc]; block 0 zeroes
// counters + out (stream-serial before K2, so replays are clean).
__global__ __launch_bounds__(256) void proto_prep(
    const float* __restrict__ in, unsigned short* __restrict__ P,
    float* __restrict__ pnp, int* __restrict__ counters, float* __restrict__ out)
{
    const int b = blockIdx.x, t = threadIdx.x;
    const int c = b >> 2, dc = b & 3;
    const int d = dc * 1024 + t * 4;
    const float* base = in + (size_t)c * (NSUP + NQRY) * DIM + d;

    float4 s0 = *(const float4*)(base + 0 * DIM);
    float4 s1 = *(const float4*)(base + 1 * DIM);
    float4 s2 = *(const float4*)(base + 2 * DIM);
    float4 s3 = *(const float4*)(base + 3 * DIM);
    float4 s4 = *(const float4*)(base + 4 * DIM);
    float ax = 0.2f * (s0.x + s1.x + s2.x + s3.x + s4.x);
    float ay = 0.2f * (s0.y + s1.y + s2.y + s3.y + s4.y);
    float az = 0.2f * (s0.z + s1.z + s2.z + s3.z + s4.z);
    float aw = 0.2f * (s0.w + s1.w + s2.w + s3.w + s4.w);
    ushort4 o;
    o.x = f2bf(ax); o.y = f2bf(ay); o.z = f2bf(az); o.w = f2bf(aw);
    *(ushort4*)(P + (size_t)c * DIM + d) = o;

    // ||p||^2 from the ROUNDED values (consistent with the 2*q.p MFMA term)
    float rx = bf2f(o.x), ry = bf2f(o.y), rz = bf2f(o.z), rw = bf2f(o.w);
    float pn = rx * rx + ry * ry + rz * rz + rw * rw;

    #pragma unroll
    for (int m = 32; m > 0; m >>= 1) pn += __shfl_xor(pn, m);
    __shared__ float red[4];
    if ((t & 63) == 0) red[t >> 6] = pn;
    __syncthreads();
    if (t == 0) pnp[c * 4 + dc] = red[0] + red[1] + red[2] + red[3];
    if (b == 0) {
        if (t < NQT) counters[t] = 0;
        if (t == 64) { out[0] = 0.f; out[1] = 0.f; }
    }
}

// K2: 240 blocks (60 q-tiles x 4 K-chunks) x 256 threads (4 waves).
// Block computes partial 16x64 score tile over its K=1024 chunk; the last
// block per q-tile (counter) reduces the 4 partials + fused softmax/argmax.
__global__ __launch_bounds__(256) void proto_main(
    const float* __restrict__ in, const unsigned short* __restrict__ P,
    const float* __restrict__ pnp, float* __restrict__ partials,
    int* __restrict__ counters, float* __restrict__ out)
{
    __shared__ float part[4 * 16 * 66];   // [wave][row][col], stride 66 (bank-pad)
    __shared__ int   is_last;
    __shared__ float red_l[4], red_a[4];

    const int tid = threadIdx.x;
    const int w = tid >> 6, lane = tid & 63;
    const int m = lane & 15;       // A row (query) / B col (class)
    const int g = lane >> 4;       // k-group within MFMA step
    const int qt = blockIdx.x / KC, kc = blockIdx.x % KC;
    const int qbase = qt * 16;
    const int kbase = kc * 1024 + w * 256;

    // A: query row qbase+m, fp32 from the original input (on-the-fly bf16 pack)
    const int qi0 = qbase + m;
    const int rowA = (qi0 / NQRY) * (NSUP + NQRY) + NSUP + (qi0 % NQRY);
    const float* ap = in + (size_t)rowA * DIM + kbase + g * 8;
    const unsigned short* bp = P + (size_t)m * DIM + kbase + g * 8;

    f32x4 acc[4];
    #pragma unroll
    for (int i = 0; i < 4; ++i) acc[i] = (f32x4){0.f, 0.f, 0.f, 0.f};

    #pragma unroll
    for (int s = 0; s < 8; ++s) {
        const int ko = s * 32;
        float4 a0 = *(const float4*)(ap + ko);
        float4 a1 = *(const float4*)(ap + ko + 4);
        unsigned p0 = __builtin_amdgcn_perm(__float_as_uint(a0.y), __float_as_uint(a0.x), 0x07060302u);
        unsigned p1 = __builtin_amdgcn_perm(__float_as_uint(a0.w), __float_as_uint(a0.z), 0x07060302u);
        unsigned p2 = __builtin_amdgcn_perm(__float_as_uint(a1.y), __float_as_uint(a1.x), 0x07060302u);
        unsigned p3 = __builtin_amdgcn_perm(__float_as_uint(a1.w), __float_as_uint(a1.z), 0x07060302u);
        union { unsigned u[4]; short8 v; } au;
        au.u[0] = p0; au.u[1] = p1; au.u[2] = p2; au.u[3] = p3;
        short8 af = au.v;

        short8 b0 = *(const short8*)(bp + ko);
        short8 b1 = *(const short8*)(bp + ko + 16 * DIM);
        short8 b2 = *(const short8*)(bp + ko + 32 * DIM);
        short8 b3 = *(const short8*)(bp + ko + 48 * DIM);
        acc[0] = __builtin_amdgcn_mfma_f32_16x16x32_bf16(af, b0, acc[0], 0, 0, 0);
        acc[1] = __builtin_amdgcn_mfma_f32_16x16x32_bf16(af, b1, acc[1], 0, 0, 0);
        acc[2] = __builtin_amdgcn_mfma_f32_16x16x32_bf16(af, b2, acc[2], 0, 0, 0);
        acc[3] = __builtin_amdgcn_mfma_f32_16x16x32_bf16(af, b3, acc[3], 0, 0, 0);
    }

    // LDS partial store: C layout col=lane&15, row=(lane>>4)*4+j  [m89]
    #pragma unroll
    for (int cg = 0; cg < 4; ++cg) {
        #pragma unroll
        for (int j = 0; j < 4; ++j)
            part[(w * 16 + g * 4 + j) * 66 + cg * 16 + m] = acc[cg][j];
    }
    __syncthreads();

    // reduce the 4 waves' partials -> global partial tile [16][64]
    {
        const int col = tid & 63, r4 = tid >> 6;
        #pragma unroll
        for (int rr = 0; rr < 4; ++rr) {
            const int row = r4 * 4 + rr;
            float v = part[(0 * 16 + row) * 66 + col] + part[(1 * 16 + row) * 66 + col]
                    + part[(2 * 16 + row) * 66 + col] + part[(3 * 16 + row) * 66 + col];
            partials[(size_t)(qt * KC + kc) * 1024 + row * 64 + col] = v;
        }
    }
    __syncthreads();

    if (tid == 0) {
        __threadfence();                        // release partial tile
        int old = atomicAdd(&counters[qt], 1);  // device-scope
        is_last = (old == KC - 1);
    }
    __syncthreads();
    if (!is_last) return;
    __threadfence();                            // acquire others' tiles

    // last block of this q-tile: reduce over kc + fused log_softmax/argmax
    const int col = tid & 63, wv = tid >> 6;
    float sl = 0.f, sa = 0.f;
    #pragma unroll
    for (int rr = 0; rr < 4; ++rr) {
        const int row = wv * 4 + rr;
        float v = 0.f;
        #pragma unroll
        for (int k2 = 0; k2 < KC; ++k2)
            v += partials[(size_t)(qt * KC + k2) * 1024 + row * 64 + col];
        float4 pp = *(const float4*)(pnp + col * 4);
        v = 2.f * v - (pp.x + pp.y + pp.z + pp.w);

        float mx = v; int am = col;
        #pragma unroll
        for (int msk = 1; msk < 64; msk <<= 1) {
            float vo = __shfl_xor(mx, msk);
            int   ao = __shfl_xor(am, msk);
            if (vo > mx || (vo == mx && ao < am)) { mx = vo; am = ao; }
        }
        float se = __expf(v - mx);
        #pragma unroll
        for (int msk = 1; msk < 64; msk <<= 1) se += __shfl_xor(se, msk);
        const float lse = mx + __logf(se);

        const int cc = (qbase + row) / NQRY;    // correct class (uniform per row)
        const float vc = __shfl(v, cc);
        if (col == 0) {
            sl += vc - lse;
            sa += (am == cc) ? 1.f : 0.f;
        }
    }
    if (col == 0) { red_l[wv] = sl; red_a[wv] = sa; }
    __syncthreads();
    if (tid == 0) {
        float tl = red_l[0] + red_l[1] + red_l[2] + red_l[3];
        float ta = red_a[0] + red_a[1] + red_a[2] + red_a[3];
        atomicAdd(out + 0, tl * (-1.f / (float)NQTOT));
        atomicAdd(out + 1, ta * (1.f / (float)NQTOT));
    }
}

extern "C" void kernel_launch(void* const* d_in, const int* in_sizes, int n_in,
                              void* d_out, int out_size, void* d_ws, size_t ws_size,
                              hipStream_t stream) {
    const float* in = (const float*)d_in[0];
    float* out = (float*)d_out;
    char* ws = (char*)d_ws;

    unsigned short* P   = (unsigned short*)ws;            // 524288 B
    float* pnp          = (float*)(ws + 524288);          // 1024 B
    int*   counters     = (int*)(ws + 525312);            // 240 B (pad 256)
    float* partials     = (float*)(ws + 525568);          // 60*4*1024*4 = 983040 B

    hipLaunchKernelGGL(proto_prep, dim3(256), dim3(256), 0, stream,
                       in, P, pnp, counters, out);
    hipLaunchKernelGGL(proto_main, dim3(NQT * KC), dim3(256), 0, stream,
                       in, P, pnp, partials, counters, out);
}